// Round 2
// baseline (17.956 us; speedup 1.0000x reference)
//
#include <hip/hip_runtime.h>
#include <math.h>

#define THREADS 256
#define SUBS 8            // lanes per pixel (faces strided by 8)
#define TILE_W 8          // wave covers an 8-pixel row segment
#define TILE_H 4          // block = 4 waves = 8x4 pixel tile
#define IMG_W 128
#define IMG_H 128
#define UNROLL 4          // faces-per-lane between early-exit checks

// face record = 3 x float4 (48B):
//   r0: v0x v0y e01x e01y
//   r1: e12x e12y e20x e20y
//   r2: inv01 inv12 inv20 area

__global__ void build_records_kernel(const float* __restrict__ verts,
                                     const int*   __restrict__ faces,
                                     const float* __restrict__ focal,
                                     const float* __restrict__ princ,
                                     float4* __restrict__ recs,
                                     int F, int Fpad)
{
    const int f = blockIdx.x * blockDim.x + threadIdx.x;
    if (f >= Fpad) return;

    const float fclx = focal[0] * (2.0f / 128.0f);
    const float fcly = focal[1] * (2.0f / 128.0f);
    const float prx  = -(princ[0] - 64.0f) * (2.0f / 128.0f);
    const float pry  = -(princ[1] - 64.0f) * (2.0f / 128.0f);

    float v0x, v0y, v1x, v1y, v2x, v2y;
    bool dummy = (f >= F);
    if (!dummy) {
        const int i0 = faces[3 * f + 0];
        const int i1 = faces[3 * f + 1];
        const int i2 = faces[3 * f + 2];
        const float x0 = verts[3 * i0], y0 = verts[3 * i0 + 1], z0 = verts[3 * i0 + 2];
        const float x1 = verts[3 * i1], y1 = verts[3 * i1 + 1], z1 = verts[3 * i1 + 2];
        const float x2 = verts[3 * i2], y2 = verts[3 * i2 + 1], z2 = verts[3 * i2 + 2];
        const float rz0 = __builtin_amdgcn_rcpf(z0);
        const float rz1 = __builtin_amdgcn_rcpf(z1);
        const float rz2 = __builtin_amdgcn_rcpf(z2);
        v0x = -fclx * (x0 * rz0) + prx;
        v0y = -fcly * (y0 * rz0) + pry;
        v1x = -fclx * (x1 * rz1) + prx;
        v1y = -fcly * (y1 * rz1) + pry;
        v2x = -fclx * (x2 * rz2) + prx;
        v2y = -fcly * (y2 * rz2) + pry;
        if (!(fminf(fminf(z0, z1), z2) > 0.01f)) dummy = true;
    }
    if (dummy) {
        // far, non-degenerate tiny triangle: inside=false, m2 huge -> q = 1 exactly
        v0x = 1000.0f;  v0y = 1000.0f;
        v1x = 1000.01f; v1y = 1000.0f;
        v2x = 1000.0f;  v2y = 1000.01f;
    }

    const float e01x = v1x - v0x, e01y = v1y - v0y;
    const float e12x = v2x - v1x, e12y = v2y - v1y;
    const float e20x = v0x - v2x, e20y = v0y - v2y;
    // area = cross(v1-v0, v2-v0); v2-v0 = -e20
    const float area = e01x * (v2y - v0y) - e01y * (v2x - v0x);

    const float inv01 = __builtin_amdgcn_rcpf(fmaxf(e01x * e01x + e01y * e01y, 1e-12f));
    const float inv12 = __builtin_amdgcn_rcpf(fmaxf(e12x * e12x + e12y * e12y, 1e-12f));
    const float inv20 = __builtin_amdgcn_rcpf(fmaxf(e20x * e20x + e20y * e20y, 1e-12f));

    recs[f * 3 + 0] = make_float4(v0x, v0y, e01x, e01y);
    recs[f * 3 + 1] = make_float4(e12x, e12y, e20x, e20y);
    recs[f * 3 + 2] = make_float4(inv01, inv12, inv20, area);
}

__device__ __forceinline__ float groupProd8(float v) {
    v *= __shfl_xor(v, 1);
    v *= __shfl_xor(v, 2);
    v *= __shfl_xor(v, 4);
    return v;
}

__global__ __launch_bounds__(THREADS)
void render_mask_kernel(const float4* __restrict__ recs,
                        float* __restrict__ out,
                        int ngroups)
{
    const int tid  = threadIdx.x;
    const int lane = tid & 63;
    const int sub  = lane & 7;       // which face-stride slot
    const int piw  = lane >> 3;      // pixel within wave: 0..7 (row segment)
    const int wave = tid >> 6;       // 0..3 -> row within tile

    const int bx = blockIdx.x & 15;         // 128/8  = 16 tiles across
    const int by = blockIdx.x >> 4;         // 128/4  = 32 tiles down
    const int c  = bx * TILE_W + piw;
    const int rr = by * TILE_H + wave;

    const float px = 1.0f - (2.0f * (float)c  + 1.0f) * (1.0f / 128.0f);
    const float py = 1.0f - (2.0f * (float)rr + 1.0f) * (1.0f / 128.0f);

    const float BLURF = 9.2102403669758494e-04f;  // log(1/1e-4 - 1) * 1e-4
    const float INV_SIGMA = 1.0e4f;

    float prod = 1.0f;

    for (int g = 0; g < ngroups; ++g) {
#pragma unroll
        for (int u = 0; u < UNROLL; ++u) {
            const int f = (g * UNROLL + u) * SUBS + sub;
            const float4 r0 = recs[f * 3 + 0];
            const float4 r1 = recs[f * 3 + 1];
            const float4 r2 = recs[f * 3 + 2];

            const float d0x = px - r0.x, d0y = py - r0.y;        // p - v0
            const float e01x = r0.z, e01y = r0.w;
            const float e12x = r1.x, e12y = r1.y;
            const float e20x = r1.z, e20y = r1.w;
            const float d1x = d0x - e01x, d1y = d0y - e01y;      // p - v1
            const float d2x = d0x + e20x, d2y = d0y + e20y;      // p - v2

            const float w0 = e12x * d1y - e12y * d1x;
            const float w1 = e20x * d2y - e20y * d2x;
            const float w2 = e01x * d0y - e01y * d0x;
            const float area = r2.w;
            const bool inside = (w0 * area >= 0.0f) && (w1 * area >= 0.0f) && (w2 * area >= 0.0f);

            float t, rx, ry, m2;
            t  = fminf(fmaxf((d0x * e01x + d0y * e01y) * r2.x, 0.0f), 1.0f);
            rx = d0x - t * e01x; ry = d0y - t * e01y;
            m2 = rx * rx + ry * ry;
            t  = fminf(fmaxf((d1x * e12x + d1y * e12y) * r2.y, 0.0f), 1.0f);
            rx = d1x - t * e12x; ry = d1y - t * e12y;
            m2 = fminf(m2, rx * rx + ry * ry);
            t  = fminf(fmaxf((d2x * e20x + d2y * e20y) * r2.z, 0.0f), 1.0f);
            rx = d2x - t * e20x; ry = d2y - t * e20y;
            m2 = fminf(m2, rx * rx + ry * ry);

            const float s = inside ? -m2 : m2;
            const float e = __expf(fminf(s, BLURF) * INV_SIGMA);
            const float q = (s <= BLURF) ? (e * __builtin_amdgcn_rcpf(1.0f + e)) : 1.0f;
            prod *= q;
        }
        // wave-uniform early exit: product is monotone non-increasing
        if (__all(groupProd8(prod) < 1e-25f)) break;
    }

    const float total = groupProd8(prod);
    if (sub == 0) {
        out[rr * IMG_W + c] = 1.0f - total;
    }
}

extern "C" void kernel_launch(void* const* d_in, const int* in_sizes, int n_in,
                              void* d_out, int out_size, void* d_ws, size_t ws_size,
                              hipStream_t stream) {
    const float* verts = (const float*)d_in[0];
    const int*   faces = (const int*)d_in[1];
    const float* focal = (const float*)d_in[2];
    const float* princ = (const float*)d_in[3];
    float* out = (float*)d_out;

    const int F = in_sizes[1] / 3;
    const int FACES_PER_GROUP = SUBS * UNROLL;                  // 32
    const int Fpad = ((F + FACES_PER_GROUP - 1) / FACES_PER_GROUP) * FACES_PER_GROUP;
    const int ngroups = Fpad / FACES_PER_GROUP;

    float4* recs = (float4*)d_ws;   // Fpad * 48 bytes needed (~74 KB)

    const int ablocks = (Fpad + THREADS - 1) / THREADS;
    hipLaunchKernelGGL(build_records_kernel, dim3(ablocks), dim3(THREADS), 0, stream,
                       verts, faces, focal, princ, recs, F, Fpad);

    const int tiles = (IMG_W / TILE_W) * (IMG_H / TILE_H);      // 512 blocks
    hipLaunchKernelGGL(render_mask_kernel, dim3(tiles), dim3(THREADS), 0, stream,
                       recs, out, ngroups);
}

// Round 3
// 15.067 us; speedup vs baseline: 1.1917x; 1.1917x over previous
//
#include <hip/hip_runtime.h>
#include <math.h>

#define THREADS 256
#define IMG_W 128
#define IMG_H 128
#define SUBS 64           // one full wave per pixel; faces strided by 64

// face record = 3 x float4 (48B):
//   r0: v0x v0y e01x e01y
//   r1: e12x e12y e20x e20y
//   r2: inv01 inv12 inv20 area

__global__ void build_records_kernel(const float* __restrict__ verts,
                                     const int*   __restrict__ faces,
                                     const float* __restrict__ focal,
                                     const float* __restrict__ princ,
                                     float4* __restrict__ recs,
                                     int F, int Fpad)
{
    const int f = blockIdx.x * blockDim.x + threadIdx.x;
    if (f >= Fpad) return;

    const float fclx = focal[0] * (2.0f / 128.0f);
    const float fcly = focal[1] * (2.0f / 128.0f);
    const float prx  = -(princ[0] - 64.0f) * (2.0f / 128.0f);
    const float pry  = -(princ[1] - 64.0f) * (2.0f / 128.0f);

    float v0x, v0y, v1x, v1y, v2x, v2y;
    bool dummy = (f >= F);
    if (!dummy) {
        const int i0 = faces[3 * f + 0];
        const int i1 = faces[3 * f + 1];
        const int i2 = faces[3 * f + 2];
        const float x0 = verts[3 * i0], y0 = verts[3 * i0 + 1], z0 = verts[3 * i0 + 2];
        const float x1 = verts[3 * i1], y1 = verts[3 * i1 + 1], z1 = verts[3 * i1 + 2];
        const float x2 = verts[3 * i2], y2 = verts[3 * i2 + 1], z2 = verts[3 * i2 + 2];
        const float rz0 = __builtin_amdgcn_rcpf(z0);
        const float rz1 = __builtin_amdgcn_rcpf(z1);
        const float rz2 = __builtin_amdgcn_rcpf(z2);
        v0x = -fclx * (x0 * rz0) + prx;
        v0y = -fcly * (y0 * rz0) + pry;
        v1x = -fclx * (x1 * rz1) + prx;
        v1y = -fcly * (y1 * rz1) + pry;
        v2x = -fclx * (x2 * rz2) + prx;
        v2y = -fcly * (y2 * rz2) + pry;
        if (!(fminf(fminf(z0, z1), z2) > 0.01f)) dummy = true;
    }
    if (dummy) {
        // far, non-degenerate tiny triangle: inside=false, m2 huge -> q = 1 exactly
        v0x = 1000.0f;  v0y = 1000.0f;
        v1x = 1000.01f; v1y = 1000.0f;
        v2x = 1000.0f;  v2y = 1000.01f;
    }

    const float e01x = v1x - v0x, e01y = v1y - v0y;
    const float e12x = v2x - v1x, e12y = v2y - v1y;
    const float e20x = v0x - v2x, e20y = v0y - v2y;
    const float area = e01x * (v2y - v0y) - e01y * (v2x - v0x);

    const float inv01 = __builtin_amdgcn_rcpf(fmaxf(e01x * e01x + e01y * e01y, 1e-12f));
    const float inv12 = __builtin_amdgcn_rcpf(fmaxf(e12x * e12x + e12y * e12y, 1e-12f));
    const float inv20 = __builtin_amdgcn_rcpf(fmaxf(e20x * e20x + e20y * e20y, 1e-12f));

    recs[f * 3 + 0] = make_float4(v0x, v0y, e01x, e01y);
    recs[f * 3 + 1] = make_float4(e12x, e12y, e20x, e20y);
    recs[f * 3 + 2] = make_float4(inv01, inv12, inv20, area);
}

__device__ __forceinline__ float waveProd64(float v) {
    v *= __shfl_xor(v, 1);
    v *= __shfl_xor(v, 2);
    v *= __shfl_xor(v, 4);
    v *= __shfl_xor(v, 8);
    v *= __shfl_xor(v, 16);
    v *= __shfl_xor(v, 32);
    return v;
}

__global__ __launch_bounds__(THREADS)
void render_mask_kernel(const float4* __restrict__ recs,
                        float* __restrict__ out,
                        int niter)
{
    const int tid  = threadIdx.x;
    const int lane = tid & 63;
    const int wave = tid >> 6;                  // 0..3
    const int pix  = blockIdx.x * 4 + wave;     // one pixel per wave

    const int c  = pix & (IMG_W - 1);
    const int rr = pix >> 7;

    const float px = 1.0f - (2.0f * (float)c  + 1.0f) * (1.0f / 128.0f);
    const float py = 1.0f - (2.0f * (float)rr + 1.0f) * (1.0f / 128.0f);

    const float BLURF = 9.2102403669758494e-04f;  // log(1/1e-4 - 1) * 1e-4
    const float INV_SIGMA = 1.0e4f;

    float prod = 1.0f;
    float total = 1.0f;

    for (int it = 0; it < niter; ++it) {
        const int f = it * SUBS + lane;
        const float4 r0 = recs[f * 3 + 0];
        const float4 r1 = recs[f * 3 + 1];
        const float4 r2 = recs[f * 3 + 2];

        const float d0x = px - r0.x, d0y = py - r0.y;        // p - v0
        const float e01x = r0.z, e01y = r0.w;
        const float e12x = r1.x, e12y = r1.y;
        const float e20x = r1.z, e20y = r1.w;
        const float d1x = d0x - e01x, d1y = d0y - e01y;      // p - v1
        const float d2x = d0x + e20x, d2y = d0y + e20y;      // p - v2

        const float w0 = e12x * d1y - e12y * d1x;
        const float w1 = e20x * d2y - e20y * d2x;
        const float w2 = e01x * d0y - e01y * d0x;
        const float area = r2.w;
        const bool inside = (w0 * area >= 0.0f) && (w1 * area >= 0.0f) && (w2 * area >= 0.0f);

        float t, rx, ry, m2;
        t  = fminf(fmaxf((d0x * e01x + d0y * e01y) * r2.x, 0.0f), 1.0f);
        rx = d0x - t * e01x; ry = d0y - t * e01y;
        m2 = rx * rx + ry * ry;
        t  = fminf(fmaxf((d1x * e12x + d1y * e12y) * r2.y, 0.0f), 1.0f);
        rx = d1x - t * e12x; ry = d1y - t * e12y;
        m2 = fminf(m2, rx * rx + ry * ry);
        t  = fminf(fmaxf((d2x * e20x + d2y * e20y) * r2.z, 0.0f), 1.0f);
        rx = d2x - t * e20x; ry = d2y - t * e20y;
        m2 = fminf(m2, rx * rx + ry * ry);

        const float s = inside ? -m2 : m2;
        const float e = __expf(fminf(s, BLURF) * INV_SIGMA);
        const float q = (s <= BLURF) ? (e * __builtin_amdgcn_rcpf(1.0f + e)) : 1.0f;
        prod *= q;

        // wave-uniform early exit; truncation error <= 1e-25 (q in [0,1])
        total = waveProd64(prod);
        if (total < 1e-25f) break;
    }

    if (lane == 0) {
        out[pix] = 1.0f - total;
    }
}

extern "C" void kernel_launch(void* const* d_in, const int* in_sizes, int n_in,
                              void* d_out, int out_size, void* d_ws, size_t ws_size,
                              hipStream_t stream) {
    const float* verts = (const float*)d_in[0];
    const int*   faces = (const int*)d_in[1];
    const float* focal = (const float*)d_in[2];
    const float* princ = (const float*)d_in[3];
    float* out = (float*)d_out;

    const int F = in_sizes[1] / 3;
    const int Fpad = ((F + SUBS - 1) / SUBS) * SUBS;
    const int niter = Fpad / SUBS;

    float4* recs = (float4*)d_ws;   // Fpad * 48 bytes (~75 KB)

    const int ablocks = (Fpad + THREADS - 1) / THREADS;
    hipLaunchKernelGGL(build_records_kernel, dim3(ablocks), dim3(THREADS), 0, stream,
                       verts, faces, focal, princ, recs, F, Fpad);

    const int pixels = IMG_W * IMG_H;
    const int rblocks = pixels / 4;             // 4096 blocks, one wave per pixel
    hipLaunchKernelGGL(render_mask_kernel, dim3(rblocks), dim3(THREADS), 0, stream,
                       recs, out, niter);
}

// Round 4
// 13.458 us; speedup vs baseline: 1.3343x; 1.1196x over previous
//
#include <hip/hip_runtime.h>
#include <math.h>

#define THREADS 256
#define IMG_W 128
#define IMG_H 128
#define SUBS 64           // one full wave per pixel; faces strided by 64

__device__ __forceinline__ float waveProd64(float v) {
    v *= __shfl_xor(v, 1);
    v *= __shfl_xor(v, 2);
    v *= __shfl_xor(v, 4);
    v *= __shfl_xor(v, 8);
    v *= __shfl_xor(v, 16);
    v *= __shfl_xor(v, 32);
    return v;
}

__global__ __launch_bounds__(THREADS)
void render_mask_fused_kernel(const float* __restrict__ verts,
                              const int*   __restrict__ faces,
                              const float* __restrict__ focal,
                              const float* __restrict__ princ,
                              float* __restrict__ out,
                              int F, int niter)
{
    const int tid  = threadIdx.x;
    const int lane = tid & 63;
    const int wave = tid >> 6;                  // 0..3
    const int pix  = blockIdx.x * 4 + wave;     // one pixel per wave

    const int c  = pix & (IMG_W - 1);
    const int rr = pix >> 7;

    const float fclx = focal[0] * (2.0f / 128.0f);
    const float fcly = focal[1] * (2.0f / 128.0f);
    const float prx  = -(princ[0] - 64.0f) * (2.0f / 128.0f);
    const float pry  = -(princ[1] - 64.0f) * (2.0f / 128.0f);

    const float px = 1.0f - (2.0f * (float)c  + 1.0f) * (1.0f / 128.0f);
    const float py = 1.0f - (2.0f * (float)rr + 1.0f) * (1.0f / 128.0f);

    const float BLURF = 9.2102403669758494e-04f;  // log(1/1e-4 - 1) * 1e-4
    const float INV_SIGMA = 1.0e4f;

    float prod = 1.0f;

    for (int it = 0; it < niter; ++it) {
        const int f = it * SUBS + lane;

        // ---- inline face build (per lane) ----
        float v0x, v0y, v1x, v1y, v2x, v2y;
        bool dummy = (f >= F);
        if (!dummy) {
            const int i0 = faces[3 * f + 0];
            const int i1 = faces[3 * f + 1];
            const int i2 = faces[3 * f + 2];
            const float x0 = verts[3 * i0], y0 = verts[3 * i0 + 1], z0 = verts[3 * i0 + 2];
            const float x1 = verts[3 * i1], y1 = verts[3 * i1 + 1], z1 = verts[3 * i1 + 2];
            const float x2 = verts[3 * i2], y2 = verts[3 * i2 + 1], z2 = verts[3 * i2 + 2];
            const float rz0 = __builtin_amdgcn_rcpf(z0);
            const float rz1 = __builtin_amdgcn_rcpf(z1);
            const float rz2 = __builtin_amdgcn_rcpf(z2);
            v0x = -fclx * (x0 * rz0) + prx;
            v0y = -fcly * (y0 * rz0) + pry;
            v1x = -fclx * (x1 * rz1) + prx;
            v1y = -fcly * (y1 * rz1) + pry;
            v2x = -fclx * (x2 * rz2) + prx;
            v2y = -fcly * (y2 * rz2) + pry;
            if (!(fminf(fminf(z0, z1), z2) > 0.01f)) dummy = true;
        }
        if (dummy) {
            // far tiny triangle: inside=false, m2 huge -> q = 1 exactly
            v0x = 1000.0f;  v0y = 1000.0f;
            v1x = 1000.01f; v1y = 1000.0f;
            v2x = 1000.0f;  v2y = 1000.01f;
        }

        const float e01x = v1x - v0x, e01y = v1y - v0y;
        const float e12x = v2x - v1x, e12y = v2y - v1y;
        const float e20x = v0x - v2x, e20y = v0y - v2y;
        const float area = e01x * (v2y - v0y) - e01y * (v2x - v0x);

        const float inv01 = __builtin_amdgcn_rcpf(fmaxf(e01x * e01x + e01y * e01y, 1e-12f));
        const float inv12 = __builtin_amdgcn_rcpf(fmaxf(e12x * e12x + e12y * e12y, 1e-12f));
        const float inv20 = __builtin_amdgcn_rcpf(fmaxf(e20x * e20x + e20y * e20y, 1e-12f));

        // ---- evaluate pixel vs face ----
        const float d0x = px - v0x, d0y = py - v0y;
        const float d1x = px - v1x, d1y = py - v1y;
        const float d2x = px - v2x, d2y = py - v2y;

        const float w0 = e12x * d1y - e12y * d1x;
        const float w1 = e20x * d2y - e20y * d2x;
        const float w2 = e01x * d0y - e01y * d0x;
        const bool inside = (w0 * area >= 0.0f) && (w1 * area >= 0.0f) && (w2 * area >= 0.0f);

        float t, rx, ry, m2;
        t  = fminf(fmaxf((d0x * e01x + d0y * e01y) * inv01, 0.0f), 1.0f);
        rx = d0x - t * e01x; ry = d0y - t * e01y;
        m2 = rx * rx + ry * ry;
        t  = fminf(fmaxf((d1x * e12x + d1y * e12y) * inv12, 0.0f), 1.0f);
        rx = d1x - t * e12x; ry = d1y - t * e12y;
        m2 = fminf(m2, rx * rx + ry * ry);
        t  = fminf(fmaxf((d2x * e20x + d2y * e20y) * inv20, 0.0f), 1.0f);
        rx = d2x - t * e20x; ry = d2y - t * e20y;
        m2 = fminf(m2, rx * rx + ry * ry);

        const float s = inside ? -m2 : m2;
        const float e = __expf(fminf(s, BLURF) * INV_SIGMA);
        const float q = (s <= BLURF) ? (e * __builtin_amdgcn_rcpf(1.0f + e)) : 1.0f;
        prod *= q;

        // sufficient early exit: q in [0,1] => wave product <= min lane prod.
        // If any lane < 1e-25, total < 1e-25 and 1-total rounds to 1.0f exactly.
        if (__any(prod < 1e-25f)) break;
    }

    const float total = waveProd64(prod);
    if (lane == 0) {
        out[pix] = (total < 1e-25f) ? 1.0f : (1.0f - total);
    }
}

extern "C" void kernel_launch(void* const* d_in, const int* in_sizes, int n_in,
                              void* d_out, int out_size, void* d_ws, size_t ws_size,
                              hipStream_t stream) {
    const float* verts = (const float*)d_in[0];
    const int*   faces = (const int*)d_in[1];
    const float* focal = (const float*)d_in[2];
    const float* princ = (const float*)d_in[3];
    float* out = (float*)d_out;

    const int F = in_sizes[1] / 3;
    const int niter = (F + SUBS - 1) / SUBS;

    const int pixels = IMG_W * IMG_H;
    const int rblocks = pixels / 4;             // 4096 blocks, one wave per pixel
    hipLaunchKernelGGL(render_mask_fused_kernel, dim3(rblocks), dim3(THREADS), 0, stream,
                       verts, faces, focal, princ, out, F, niter);
}

// Round 5
// 10.594 us; speedup vs baseline: 1.6949x; 1.2703x over previous
//
#include <hip/hip_runtime.h>
#include <math.h>

#define THREADS 1024
#define WAVES_PER_BLOCK (THREADS / 64)
#define PIX_PER_WAVE 4
#define IMG_W 128
#define IMG_H 128
#define SUBS 64           // faces strided across the 64 lanes of a wave

__device__ __forceinline__ float waveProd64(float v) {
    v *= __shfl_xor(v, 1);
    v *= __shfl_xor(v, 2);
    v *= __shfl_xor(v, 4);
    v *= __shfl_xor(v, 8);
    v *= __shfl_xor(v, 16);
    v *= __shfl_xor(v, 32);
    return v;
}

__global__ __launch_bounds__(THREADS)
void render_mask_fused4_kernel(const float* __restrict__ verts,
                               const int*   __restrict__ faces,
                               const float* __restrict__ focal,
                               const float* __restrict__ princ,
                               float* __restrict__ out,
                               int F, int niter)
{
    const int tid  = threadIdx.x;
    const int lane = tid & 63;
    const int wave = tid >> 6;                                  // 0..15
    const int pixBase = (blockIdx.x * WAVES_PER_BLOCK + wave) * PIX_PER_WAVE;

    const int c0 = pixBase & (IMG_W - 1);   // 4 consecutive columns, same row
    const int rr = pixBase >> 7;

    const float fclx = focal[0] * (2.0f / 128.0f);
    const float fcly = focal[1] * (2.0f / 128.0f);
    const float prx  = -(princ[0] - 64.0f) * (2.0f / 128.0f);
    const float pry  = -(princ[1] - 64.0f) * (2.0f / 128.0f);

    const float px0 = 1.0f - (2.0f * (float)c0 + 1.0f) * (1.0f / 128.0f);
    const float py  = 1.0f - (2.0f * (float)rr + 1.0f) * (1.0f / 128.0f);
    const float DX  = -2.0f / 128.0f;
    const float px1 = px0 + DX, px2 = px0 + 2.0f * DX, px3 = px0 + 3.0f * DX;

    const float BLURF = 9.2102403669758494e-04f;  // log(1/1e-4 - 1) * 1e-4
    const float INV_SIGMA = 1.0e4f;
    const float EPS = 1e-25f;

    float prod0 = 1.0f, prod1 = 1.0f, prod2 = 1.0f, prod3 = 1.0f;

    for (int it = 0; it < niter; ++it) {
        const int f = it * SUBS + lane;

        // ---- inline face build (per lane), shared by 4 pixels ----
        float v0x, v0y, v1x, v1y, v2x, v2y;
        bool dummy = (f >= F);
        if (!dummy) {
            const int i0 = faces[3 * f + 0];
            const int i1 = faces[3 * f + 1];
            const int i2 = faces[3 * f + 2];
            const float x0 = verts[3 * i0], y0 = verts[3 * i0 + 1], z0 = verts[3 * i0 + 2];
            const float x1 = verts[3 * i1], y1 = verts[3 * i1 + 1], z1 = verts[3 * i1 + 2];
            const float x2 = verts[3 * i2], y2 = verts[3 * i2 + 1], z2 = verts[3 * i2 + 2];
            const float rz0 = __builtin_amdgcn_rcpf(z0);
            const float rz1 = __builtin_amdgcn_rcpf(z1);
            const float rz2 = __builtin_amdgcn_rcpf(z2);
            v0x = -fclx * (x0 * rz0) + prx;
            v0y = -fcly * (y0 * rz0) + pry;
            v1x = -fclx * (x1 * rz1) + prx;
            v1y = -fcly * (y1 * rz1) + pry;
            v2x = -fclx * (x2 * rz2) + prx;
            v2y = -fcly * (y2 * rz2) + pry;
            if (!(fminf(fminf(z0, z1), z2) > 0.01f)) dummy = true;
        }
        if (dummy) {
            // far tiny triangle: inside=false, m2 huge -> q = 1 exactly
            v0x = 1000.0f;  v0y = 1000.0f;
            v1x = 1000.01f; v1y = 1000.0f;
            v2x = 1000.0f;  v2y = 1000.01f;
        }

        const float e01x = v1x - v0x, e01y = v1y - v0y;
        const float e12x = v2x - v1x, e12y = v2y - v1y;
        const float e20x = v0x - v2x, e20y = v0y - v2y;
        const float area = e01x * (v2y - v0y) - e01y * (v2x - v0x);

        const float inv01 = __builtin_amdgcn_rcpf(fmaxf(e01x * e01x + e01y * e01y, 1e-12f));
        const float inv12 = __builtin_amdgcn_rcpf(fmaxf(e12x * e12x + e12y * e12y, 1e-12f));
        const float inv20 = __builtin_amdgcn_rcpf(fmaxf(e20x * e20x + e20y * e20y, 1e-12f));

        // ---- y-dependent terms shared by all 4 pixels (same row) ----
        const float d0y = py - v0y;
        const float d1y = d0y - e01y;
        const float d2y = d0y + e20y;
        const float a0  = e12x * d1y;
        const float a1  = e20x * d2y;
        const float a2  = e01x * d0y;
        const float b01 = d0y * e01y;
        const float b12 = d1y * e12y;
        const float b20 = d2y * e20y;

#define EVAL_PIXEL(PX, PROD)                                                      \
        {                                                                         \
            const float d0x = (PX) - v0x;                                         \
            const float d1x = d0x - e01x;                                         \
            const float d2x = d0x + e20x;                                         \
            const float w0 = a0 - e12y * d1x;                                     \
            const float w1 = a1 - e20y * d2x;                                     \
            const float w2 = a2 - e01y * d0x;                                     \
            const bool inside = (w0 * area >= 0.0f) && (w1 * area >= 0.0f) &&     \
                                (w2 * area >= 0.0f);                              \
            float t, rx, ry, m2;                                                  \
            t  = fminf(fmaxf((d0x * e01x + b01) * inv01, 0.0f), 1.0f);            \
            rx = d0x - t * e01x; ry = d0y - t * e01y;                             \
            m2 = rx * rx + ry * ry;                                               \
            t  = fminf(fmaxf((d1x * e12x + b12) * inv12, 0.0f), 1.0f);            \
            rx = d1x - t * e12x; ry = d1y - t * e12y;                             \
            m2 = fminf(m2, rx * rx + ry * ry);                                    \
            t  = fminf(fmaxf((d2x * e20x + b20) * inv20, 0.0f), 1.0f);            \
            rx = d2x - t * e20x; ry = d2y - t * e20y;                             \
            m2 = fminf(m2, rx * rx + ry * ry);                                    \
            const float s = inside ? -m2 : m2;                                    \
            const float e = __expf(fminf(s, BLURF) * INV_SIGMA);                  \
            const float q = (s <= BLURF) ? (e * __builtin_amdgcn_rcpf(1.0f + e))  \
                                         : 1.0f;                                  \
            (PROD) *= q;                                                          \
        }

        EVAL_PIXEL(px0, prod0)
        EVAL_PIXEL(px1, prod1)
        EVAL_PIXEL(px2, prod2)
        EVAL_PIXEL(px3, prod3)
#undef EVAL_PIXEL

        // exit when every pixel's wave-product is provably < EPS:
        // q in [0,1] => wave product <= min lane prod, so any-lane < EPS suffices.
        const bool d0 = __any(prod0 < EPS);
        const bool d1 = __any(prod1 < EPS);
        const bool d2 = __any(prod2 < EPS);
        const bool d3 = __any(prod3 < EPS);
        if (d0 & d1 & d2 & d3) break;
    }

    // saturated pixels: 1 - total rounds to exactly 1.0f; otherwise full reduce
    const float t0 = __any(prod0 < EPS) ? 1.0f : (1.0f - waveProd64(prod0));
    const float t1 = __any(prod1 < EPS) ? 1.0f : (1.0f - waveProd64(prod1));
    const float t2 = __any(prod2 < EPS) ? 1.0f : (1.0f - waveProd64(prod2));
    const float t3 = __any(prod3 < EPS) ? 1.0f : (1.0f - waveProd64(prod3));

    if (lane == 0) {
        out[pixBase + 0] = t0;
        out[pixBase + 1] = t1;
        out[pixBase + 2] = t2;
        out[pixBase + 3] = t3;
    }
}

extern "C" void kernel_launch(void* const* d_in, const int* in_sizes, int n_in,
                              void* d_out, int out_size, void* d_ws, size_t ws_size,
                              hipStream_t stream) {
    const float* verts = (const float*)d_in[0];
    const int*   faces = (const int*)d_in[1];
    const float* focal = (const float*)d_in[2];
    const float* princ = (const float*)d_in[3];
    float* out = (float*)d_out;

    const int F = in_sizes[1] / 3;
    const int niter = (F + SUBS - 1) / SUBS;

    const int pixels = IMG_W * IMG_H;
    const int blocks = pixels / (WAVES_PER_BLOCK * PIX_PER_WAVE);   // 256
    hipLaunchKernelGGL(render_mask_fused4_kernel, dim3(blocks), dim3(THREADS), 0, stream,
                       verts, faces, focal, princ, out, F, niter);
}